// Round 3
// baseline (427.361 us; speedup 1.0000x reference)
//
#include <hip/hip_runtime.h>

#define DCH 64
#define BN_EPS 1e-5f
#define SCAN_ELEMS 2048   // per block: 256 threads x 8

// pack two fp32 -> two bf16 in one uint (lo = even channel, hi = odd channel)
__device__ __forceinline__ unsigned bf16pair(float lo, float hi) {
    unsigned ul = (__float_as_uint(lo) + 0x8000u) >> 16;
    unsigned uh = (__float_as_uint(hi) + 0x8000u) & 0xffff0000u;
    return ul | uh;
}

// ---------------------------------------------------------------------------
// K1: y = x @ W^T, output stored as bf16 (ushort). Block 256 = 128 rows.
// ---------------------------------------------------------------------------
__global__ __launch_bounds__(256) void gemm_xwt(const float* __restrict__ x,
                                                const float* __restrict__ W,
                                                unsigned short* __restrict__ yb, int N) {
    __shared__ float xs[128 * 68];
    __shared__ float wt[64 * 64];
    const int tid = threadIdx.x;
    const int blockRow = blockIdx.x * 128;

#pragma unroll
    for (int jj = 0; jj < 4; ++jj) {
        int idx4 = tid * 16 + jj * 4;
        int o = idx4 >> 6, k = idx4 & 63;
        float4 w4 = *(const float4*)&W[idx4];
        wt[(k + 0) * 64 + o] = w4.x;
        wt[(k + 1) * 64 + o] = w4.y;
        wt[(k + 2) * 64 + o] = w4.z;
        wt[(k + 3) * 64 + o] = w4.w;
    }
#pragma unroll
    for (int jj = 0; jj < 8; ++jj) {
        int f4 = tid + 256 * jj;
        int rl = f4 >> 4, k4 = (f4 & 15) * 4;
        int row = blockRow + rl;
        float4 v = make_float4(0.f, 0.f, 0.f, 0.f);
        if (row < N) v = *(const float4*)&x[row * DCH + k4];
        *(float4*)&xs[rl * 68 + k4] = v;
    }
    __syncthreads();

    const int tc = tid & 7;
    const int tr = tid >> 3;
    const int dc = tc * 8;
    float acc[4][8];
#pragma unroll
    for (int i = 0; i < 4; ++i)
#pragma unroll
        for (int j = 0; j < 8; ++j) acc[i][j] = 0.f;

#pragma unroll 4
    for (int k = 0; k < 64; ++k) {
        float4 w0 = *(const float4*)&wt[k * 64 + dc];
        float4 w1 = *(const float4*)&wt[k * 64 + dc + 4];
#pragma unroll
        for (int i = 0; i < 4; ++i) {
            float xv = xs[(tr + 32 * i) * 68 + k];
            acc[i][0] = fmaf(xv, w0.x, acc[i][0]);
            acc[i][1] = fmaf(xv, w0.y, acc[i][1]);
            acc[i][2] = fmaf(xv, w0.z, acc[i][2]);
            acc[i][3] = fmaf(xv, w0.w, acc[i][3]);
            acc[i][4] = fmaf(xv, w1.x, acc[i][4]);
            acc[i][5] = fmaf(xv, w1.y, acc[i][5]);
            acc[i][6] = fmaf(xv, w1.z, acc[i][6]);
            acc[i][7] = fmaf(xv, w1.w, acc[i][7]);
        }
    }
#pragma unroll
    for (int i = 0; i < 4; ++i) {
        int row = blockRow + tr + 32 * i;
        if (row < N) {
            uint4 p;
            p.x = bf16pair(acc[i][0], acc[i][1]);
            p.y = bf16pair(acc[i][2], acc[i][3]);
            p.z = bf16pair(acc[i][4], acc[i][5]);
            p.w = bf16pair(acc[i][6], acc[i][7]);
            *(uint4*)&yb[row * DCH + dc] = p;
        }
    }
}

// --------------------------- CSR build ------------------------------------
__global__ __launch_bounds__(256) void hist_rows(const int* __restrict__ rows,
                                                 int* __restrict__ count, int E) {
    int e = blockIdx.x * 256 + threadIdx.x;
    if (e < E) atomicAdd(&count[rows[e]], 1);
}

__global__ __launch_bounds__(256) void scan_p1(const int* __restrict__ count,
                                               int* __restrict__ blocksum, int N) {
    __shared__ int sdata[256];
    const int tid = threadIdx.x;
    const int base = blockIdx.x * SCAN_ELEMS + tid * 8;
    int s = 0;
#pragma unroll
    for (int j = 0; j < 8; ++j) {
        int i = base + j;
        if (i < N) s += count[i];
    }
    sdata[tid] = s;
    __syncthreads();
    for (int off = 128; off > 0; off >>= 1) {
        if (tid < off) sdata[tid] += sdata[tid + off];
        __syncthreads();
    }
    if (tid == 0) blocksum[blockIdx.x] = sdata[0];
}

__global__ void scan_p2(int* __restrict__ blocksum, int* __restrict__ rowptr,
                        int nb, int N) {
    if (threadIdx.x == 0 && blockIdx.x == 0) {
        int run = 0;
        for (int b = 0; b < nb; ++b) {
            int t = blocksum[b];
            blocksum[b] = run;
            run += t;
        }
        rowptr[N] = run;
    }
}

__global__ __launch_bounds__(256) void scan_p3(const int* __restrict__ count,
                                               const int* __restrict__ blocksum,
                                               int* __restrict__ rowptr,
                                               int* __restrict__ cursor, int N) {
    __shared__ int sdata[256];
    const int tid = threadIdx.x;
    const int base = blockIdx.x * SCAN_ELEMS + tid * 8;
    int v[8];
    int tsum = 0;
#pragma unroll
    for (int j = 0; j < 8; ++j) {
        int i = base + j;
        v[j] = (i < N) ? count[i] : 0;
        tsum += v[j];
    }
    sdata[tid] = tsum;
    __syncthreads();
    for (int off = 1; off < 256; off <<= 1) {
        int mine = sdata[tid];
        int add = (tid >= off) ? sdata[tid - off] : 0;
        __syncthreads();
        sdata[tid] = mine + add;
        __syncthreads();
    }
    int run = blocksum[blockIdx.x] + sdata[tid] - tsum;  // exclusive
#pragma unroll
    for (int j = 0; j < 8; ++j) {
        int i = base + j;
        if (i < N) {
            rowptr[i] = run;
            cursor[i] = run;
            run += v[j];
        }
    }
}

// scatter (col,val) packed into one 8B element
__global__ __launch_bounds__(256) void scatter_edges(const int* __restrict__ rows,
                                                     const int* __restrict__ cols,
                                                     const float* __restrict__ vals,
                                                     int* __restrict__ cursor,
                                                     int2* __restrict__ edges, int E) {
    int e = blockIdx.x * 256 + threadIdx.x;
    if (e < E) {
        int r = rows[e];
        int pos = atomicAdd(&cursor[r], 1);
        int2 p;
        p.x = cols[e];
        p.y = __float_as_int(vals[e]);
        edges[pos] = p;
    }
}

// ---------------------------------------------------------------------------
// K2 fused: per-row SpMM (CSR, bf16 y) + bias + residual + stats.
// 16 lanes per edge (uint2 = 4 bf16 channels per lane), 4 edge slots per wave,
// unrolled x2 => 8 edges in flight. Cross-slot reduce: shfl_xor 16, 32.
// ---------------------------------------------------------------------------
#define ROWS_PER_WAVE 8
__global__ __launch_bounds__(256) void spmm_fused(const unsigned short* __restrict__ yb,
                                                  const int* __restrict__ rowptr,
                                                  const int2* __restrict__ edges,
                                                  const float* __restrict__ x,
                                                  const float* __restrict__ b,
                                                  float* __restrict__ out,
                                                  float* __restrict__ stats, int N) {
    const int lane = threadIdx.x & 63;
    const int wave = threadIdx.x >> 6;
    const int g = lane >> 4;    // edge slot 0..3
    const int i = lane & 15;    // channel quad 0..15
    const int rbase = (blockIdx.x * 4 + wave) * ROWS_PER_WAVE;
    const float4 bias4 = *(const float4*)&b[i * 4];
    float4 s  = make_float4(0.f, 0.f, 0.f, 0.f);
    float4 s2 = make_float4(0.f, 0.f, 0.f, 0.f);

#pragma unroll
    for (int rr = 0; rr < ROWS_PER_WAVE; ++rr) {
        int r = rbase + rr;
        if (r >= N) break;
        int beg = rowptr[r], end = rowptr[r + 1];
        float4 acc = make_float4(0.f, 0.f, 0.f, 0.f);
        for (int j = beg; j < end; j += 8) {
            int ja = j + g;
            int jb = j + 4 + g;
            int ca = 0, cb = 0;
            float va = 0.f, vb = 0.f;
            if (ja < end) { int2 p = edges[ja]; ca = p.x; va = __int_as_float(p.y); }
            if (jb < end) { int2 p = edges[jb]; cb = p.x; vb = __int_as_float(p.y); }
            uint2 qa = *(const uint2*)&yb[ca * DCH + i * 4];
            uint2 qb = *(const uint2*)&yb[cb * DCH + i * 4];
            acc.x = fmaf(va, __uint_as_float(qa.x << 16), acc.x);
            acc.y = fmaf(va, __uint_as_float(qa.x & 0xffff0000u), acc.y);
            acc.z = fmaf(va, __uint_as_float(qa.y << 16), acc.z);
            acc.w = fmaf(va, __uint_as_float(qa.y & 0xffff0000u), acc.w);
            acc.x = fmaf(vb, __uint_as_float(qb.x << 16), acc.x);
            acc.y = fmaf(vb, __uint_as_float(qb.x & 0xffff0000u), acc.y);
            acc.z = fmaf(vb, __uint_as_float(qb.y << 16), acc.z);
            acc.w = fmaf(vb, __uint_as_float(qb.y & 0xffff0000u), acc.w);
        }
        // reduce the 4 edge slots
        acc.x += __shfl_xor(acc.x, 16);
        acc.y += __shfl_xor(acc.y, 16);
        acc.z += __shfl_xor(acc.z, 16);
        acc.w += __shfl_xor(acc.w, 16);
        acc.x += __shfl_xor(acc.x, 32);
        acc.y += __shfl_xor(acc.y, 32);
        acc.z += __shfl_xor(acc.z, 32);
        acc.w += __shfl_xor(acc.w, 32);
        if (lane < 16) {
            float4 xv = *(const float4*)&x[r * DCH + i * 4];
            float4 z;
            z.x = acc.x + bias4.x + xv.x;
            z.y = acc.y + bias4.y + xv.y;
            z.z = acc.z + bias4.z + xv.z;
            z.w = acc.w + bias4.w + xv.w;
            *(float4*)&out[r * DCH + i * 4] = z;
            s.x += z.x; s.y += z.y; s.z += z.z; s.w += z.w;
            s2.x = fmaf(z.x, z.x, s2.x);
            s2.y = fmaf(z.y, z.y, s2.y);
            s2.z = fmaf(z.z, z.z, s2.z);
            s2.w = fmaf(z.w, z.w, s2.w);
        }
    }
    __shared__ float rs[4][64];
    __shared__ float rs2[4][64];
    if (lane < 16) {
        *(float4*)&rs[wave][i * 4]  = s;
        *(float4*)&rs2[wave][i * 4] = s2;
    }
    __syncthreads();
    const int tid = threadIdx.x;
    if (tid < 64) {
        float ts  = rs[0][tid] + rs[1][tid] + rs[2][tid] + rs[3][tid];
        float ts2 = rs2[0][tid] + rs2[1][tid] + rs2[2][tid] + rs2[3][tid];
        atomicAdd(&stats[tid], ts);
        atomicAdd(&stats[64 + tid], ts2);
    }
}

// ---------------------------------------------------------------------------
// K3: BatchNorm (biased var) + ReLU in place, float4.
// ---------------------------------------------------------------------------
__global__ __launch_bounds__(256) void bn_relu(float4* __restrict__ out,
                                               const float* __restrict__ stats,
                                               const float* __restrict__ gamma,
                                               const float* __restrict__ beta,
                                               int ND4, float invN) {
    const int tid = threadIdx.x;
    const int idx0 = blockIdx.x * 256 + tid;
    const int q = idx0 & 15;  // channel quad (stride is multiple of 16)
    float4 sc4, sh4;
    {
        float4 m  = *(const float4*)&stats[q * 4];
        float4 m2 = *(const float4*)&stats[64 + q * 4];
        float4 g4 = *(const float4*)&gamma[q * 4];
        float4 b4 = *(const float4*)&beta[q * 4];
        float mean, var;
        mean = m.x * invN; var = m2.x * invN - mean * mean;
        sc4.x = g4.x * rsqrtf(var + BN_EPS); sh4.x = b4.x - mean * sc4.x;
        mean = m.y * invN; var = m2.y * invN - mean * mean;
        sc4.y = g4.y * rsqrtf(var + BN_EPS); sh4.y = b4.y - mean * sc4.y;
        mean = m.z * invN; var = m2.z * invN - mean * mean;
        sc4.z = g4.z * rsqrtf(var + BN_EPS); sh4.z = b4.z - mean * sc4.z;
        mean = m.w * invN; var = m2.w * invN - mean * mean;
        sc4.w = g4.w * rsqrtf(var + BN_EPS); sh4.w = b4.w - mean * sc4.w;
    }
    const int stride = gridDim.x * 256;
    for (int i = idx0; i < ND4; i += stride) {
        float4 v = out[i];
        v.x = fmaxf(fmaf(v.x, sc4.x, sh4.x), 0.f);
        v.y = fmaxf(fmaf(v.y, sc4.y, sh4.y), 0.f);
        v.z = fmaxf(fmaf(v.z, sc4.z, sh4.z), 0.f);
        v.w = fmaxf(fmaf(v.w, sc4.w, sh4.w), 0.f);
        out[i] = v;
    }
}

extern "C" void kernel_launch(void* const* d_in, const int* in_sizes, int n_in,
                              void* d_out, int out_size, void* d_ws, size_t ws_size,
                              hipStream_t stream) {
    const float* x       = (const float*)d_in[0];
    const float* adj_val = (const float*)d_in[1];
    const float* W       = (const float*)d_in[2];
    const float* b       = (const float*)d_in[3];
    const float* gamma   = (const float*)d_in[4];
    const float* beta    = (const float*)d_in[5];
    const int*   adj_row = (const int*)d_in[6];
    const int*   adj_col = (const int*)d_in[7];
    float* out = (float*)d_out;

    const int N  = in_sizes[0] / DCH;
    const int E  = in_sizes[1];
    const int ND = N * DCH;
    const int nb = (N + SCAN_ELEMS - 1) / SCAN_ELEMS;

    char* ws = (char*)d_ws;
    size_t off = 0;
    float* stats  = (float*)(ws + off); off += 4096;
    int* count    = (int*)(ws + off);   off += ((size_t)N * 4 + 127) & ~127ull;
    int* cursor   = (int*)(ws + off);   off += ((size_t)N * 4 + 127) & ~127ull;
    int* rowptr   = (int*)(ws + off);   off += ((size_t)(N + 1) * 4 + 127) & ~127ull;
    int* blocksum = (int*)(ws + off);   off += ((size_t)(nb + 1) * 4 + 127) & ~127ull;
    unsigned short* yb = (unsigned short*)(ws + off); off += (size_t)ND * 2;
    off = (off + 127) & ~127ull;
    int2* edges   = (int2*)(ws + off);  off += (size_t)E * 8;

    (void)hipMemsetAsync(ws, 0, 4096 + (size_t)N * 4, stream);

    gemm_xwt<<<(N + 127) / 128, 256, 0, stream>>>(x, W, yb, N);
    hist_rows<<<(E + 255) / 256, 256, 0, stream>>>(adj_row, count, E);
    scan_p1<<<nb, 256, 0, stream>>>(count, blocksum, N);
    scan_p2<<<1, 64, 0, stream>>>(blocksum, rowptr, nb, N);
    scan_p3<<<nb, 256, 0, stream>>>(count, blocksum, rowptr, cursor, N);
    scatter_edges<<<(E + 255) / 256, 256, 0, stream>>>(adj_row, adj_col, adj_val,
                                                       cursor, edges, E);
    spmm_fused<<<(N + 4 * ROWS_PER_WAVE - 1) / (4 * ROWS_PER_WAVE), 256, 0, stream>>>(
        yb, rowptr, edges, x, b, out, stats, N);
    bn_relu<<<1024, 256, 0, stream>>>((float4*)out, stats, gamma, beta, ND / 4,
                                      1.0f / (float)N);
}